// Round 4
// baseline (365.785 us; speedup 1.0000x reference)
//
#include <hip/hip_runtime.h>

// Problem constants
#define B_ 2048
#define S_ 512
#define I_ 256
#define F_ 256
#define NG 8   // partial-groups for the W2 fold

// Workspace layout (in floats)
#define OFF_W    0                       // w[B,F]   (hidden @ W1^T)
#define OFF_SW   (OFF_W + B_*F_)         // Sw[B]    (row sums of w)
#define OFF_RP   (OFF_SW + B_)           // rp[NG][512] partial r = Wfc@W2
// total floats = OFF_RP + NG*512 = 530,432 (~2.1 MB)

// ---------------------------------------------------------------------------
// k_pre: blocks 0..511  : w[b,f] = hidden[b,:].W1[f,:], Sw[b] (4 batches/block)
//        blocks 512..519: partial fold rp[g][j] = sum_{i in g's 32} Wfc[i]*W2[i,j]
__global__ __launch_bounds__(256) void k_pre(
    const float* __restrict__ hidden, const float* __restrict__ W1,
    const float* __restrict__ W2, const float* __restrict__ Wfc,
    float* __restrict__ ws) {
  const int tid = threadIdx.x;

  if (blockIdx.x >= B_ / 4) {
    const int g = blockIdx.x - B_ / 4;
    float acc0 = 0.f, acc1 = 0.f;
#pragma unroll 8
    for (int ii = 0; ii < 32; ++ii) {
      const int i = g * 32 + ii;
      const float f = Wfc[i];
      acc0 += f * W2[(size_t)i * (I_ + F_) + tid];
      acc1 += f * W2[(size_t)i * (I_ + F_) + tid + 256];
    }
    ws[OFF_RP + g * 512 + tid] = acc0;        // r_h partial
    ws[OFF_RP + g * 512 + 256 + tid] = acc1;  // r_v partial
    return;
  }

  __shared__ float h[4][I_];
  __shared__ float red[256];
  const int b0 = blockIdx.x * 4;
#pragma unroll
  for (int k = 0; k < 4; ++k) h[k][tid] = hidden[(size_t)(b0 + k) * I_ + tid];
  __syncthreads();

  const int f = tid;
  const float4* wrow = (const float4*)(W1 + (size_t)f * I_);
  float acc[4] = {0.f, 0.f, 0.f, 0.f};
#pragma unroll 4
  for (int iq = 0; iq < I_ / 4; ++iq) {
    const float4 v = wrow[iq];
    const int i = 4 * iq;
#pragma unroll
    for (int k = 0; k < 4; ++k)
      acc[k] += v.x * h[k][i] + v.y * h[k][i + 1] + v.z * h[k][i + 2] + v.w * h[k][i + 3];
  }
#pragma unroll
  for (int k = 0; k < 4; ++k) ws[OFF_W + (size_t)(b0 + k) * F_ + f] = acc[k];

#pragma unroll
  for (int k = 0; k < 4; ++k) {
    red[tid] = acc[k];
    __syncthreads();
    for (int s = 128; s > 0; s >>= 1) { if (tid < s) red[tid] += red[tid + s]; __syncthreads(); }
    if (tid == 0) ws[OFF_SW + b0 + k] = red[0];
    __syncthreads();
  }
}

// ---------------------------------------------------------------------------
// k_main: one block per batch b.
// Phase A (streaming): u[t] = inp[b,t,:].w[b,:], p[t] = inp[b,t,:].r_v[:]
//   — full-row coalesced loads (wave = 1KB row), dual 6-step shfl reduce,
//   results kept in LDS only.
// Phase B (epilogue): s[x] = Wc[x,:].u + bc[x]*Sw; a = sigmoid(s);
//   out[b] = sum_x a[x]*(q[x] + bc[x]*R) + r_h.hidden[b,:] + const0
__global__ __launch_bounds__(256) void k_main(
    const float* __restrict__ inp, const float* __restrict__ Wc,
    const float* __restrict__ bc, const float* __restrict__ b2,
    const float* __restrict__ Wfc, const float* __restrict__ bfc,
    const float* __restrict__ hidden, const float* __restrict__ wsw,
    const float* __restrict__ wsSw, const float* __restrict__ wsrp,
    float* __restrict__ out) {
  const int b = blockIdx.x;
  const int tid = threadIdx.x;
  const int lane = tid & 63;
  const int wid = tid >> 6;

  __shared__ float u_lds[S_];
  __shared__ float p_lds[S_];
  __shared__ float rv_lds[F_];
  __shared__ float redA[4], redB[4], redC[4];

  // fold r partials: rh[x]=r_h, rv[x]=r_v for x = tid
  float rh = 0.f, rv = 0.f;
#pragma unroll
  for (int g = 0; g < NG; ++g) {
    rh += wsrp[g * 512 + tid];
    rv += wsrp[g * 512 + 256 + tid];
  }
  rv_lds[tid] = rv;

  // R = sum(r_v); c0 = Wfc.b2 + bfc  (block reductions, stash per-wave)
  float t0 = rv, t1 = Wfc[tid] * b2[tid];
#pragma unroll
  for (int m = 32; m >= 1; m >>= 1) {
    t0 += __shfl_xor(t0, m, 64);
    t1 += __shfl_xor(t1, m, 64);
  }
  if (lane == 0) { redA[wid] = t0; redB[wid] = t1; }
  __syncthreads();

  // ---- Phase A ----
  const float4 w4  = ((const float4*)(wsw + (size_t)b * F_))[lane];
  const float4 rv4 = ((const float4*)rv_lds)[lane];
  const float* base = inp + (size_t)b * S_ * I_;

  for (int it = 0; it < 16; ++it) {
#pragma unroll
    for (int rr = 0; rr < 8; ++rr) {
      const int row = it * 32 + wid * 8 + rr;
      const float4 v = ((const float4*)(base + (size_t)row * I_))[lane];
      float du = v.x * w4.x + v.y * w4.y + v.z * w4.z + v.w * w4.w;
      float dp = v.x * rv4.x + v.y * rv4.y + v.z * rv4.z + v.w * rv4.w;
#pragma unroll
      for (int m = 32; m >= 1; m >>= 1) {
        du += __shfl_xor(du, m, 64);
        dp += __shfl_xor(dp, m, 64);
      }
      if (lane == 0) { u_lds[row] = du; p_lds[row] = dp; }
    }
  }
  __syncthreads();

  // ---- Phase B ----
  const float R  = redA[0] + redA[1] + redA[2] + redA[3];
  const float c0 = redB[0] + redB[1] + redB[2] + redB[3] + bfc[0];
  const float Sw = wsSw[b];
  const float bcx = bc[tid];

  const float4* wrow = (const float4*)(Wc + (size_t)tid * S_);
  float ss = 0.f, qs = 0.f;
#pragma unroll 4
  for (int tq = 0; tq < S_ / 4; ++tq) {
    const float4 cv = wrow[tq];
    const float4 uu = ((const float4*)u_lds)[tq];  // uniform -> LDS broadcast
    const float4 pp = ((const float4*)p_lds)[tq];
    ss += cv.x * uu.x + cv.y * uu.y + cv.z * uu.z + cv.w * uu.w;
    qs += cv.x * pp.x + cv.y * pp.y + cv.z * pp.z + cv.w * pp.w;
  }
  const float s = ss + bcx * Sw;
  const float a = 1.f / (1.f + expf(-s));
  float partial = a * (qs + bcx * R) + rh * hidden[(size_t)b * I_ + tid];
#pragma unroll
  for (int m = 32; m >= 1; m >>= 1) partial += __shfl_xor(partial, m, 64);
  if (lane == 0) redC[wid] = partial;
  __syncthreads();
  if (tid == 0) out[b] = redC[0] + redC[1] + redC[2] + redC[3] + c0;
}

// ---------------------------------------------------------------------------
extern "C" void kernel_launch(void* const* d_in, const int* in_sizes, int n_in,
                              void* d_out, int out_size, void* d_ws, size_t ws_size,
                              hipStream_t stream) {
  (void)in_sizes; (void)n_in; (void)out_size; (void)ws_size;
  const float* hidden = (const float*)d_in[0];
  const float* inp    = (const float*)d_in[1];
  const float* W1     = (const float*)d_in[2];
  const float* Wc     = (const float*)d_in[3];
  const float* bc     = (const float*)d_in[4];
  const float* W2     = (const float*)d_in[5];
  const float* b2     = (const float*)d_in[6];
  const float* Wfc    = (const float*)d_in[7];
  const float* bfc    = (const float*)d_in[8];
  float* out = (float*)d_out;
  float* ws  = (float*)d_ws;

  hipLaunchKernelGGL(k_pre, dim3(B_ / 4 + NG), dim3(256), 0, stream,
                     hidden, W1, W2, Wfc, ws);
  hipLaunchKernelGGL(k_main, dim3(B_), dim3(256), 0, stream,
                     inp, Wc, bc, b2, Wfc, bfc, hidden,
                     ws + OFF_W, ws + OFF_SW, ws + OFF_RP, out);
}

// Round 5
// 263.147 us; speedup vs baseline: 1.3900x; 1.3900x over previous
//
#include <hip/hip_runtime.h>

// Problem constants
#define B_ 2048
#define S_ 512
#define I_ 256
#define F_ 256
#define NG 8   // partial-groups for the W2 fold

// Workspace layout (in floats)
#define OFF_W    0                       // w[B,F]   (hidden @ W1^T)
#define OFF_SW   (OFF_W + B_*F_)         // Sw[B]    (row sums of w)
#define OFF_U    (OFF_SW + B_)           // u[B,S]
#define OFF_P    (OFF_U + B_*S_)         // p[B,S]
#define OFF_RP   (OFF_P + B_*S_)         // rp[NG][512] partial r = Wfc@W2
// total floats = OFF_RP + NG*512 = 2,628,608 (~10.5 MB)

// ---------------------------------------------------------------------------
// k_pre: blocks 0..511  : w[b,f] = hidden[b,:].W1[f,:], Sw[b] (4 batches/block)
//        blocks 512..519: partial fold rp[g][j] = sum_{i in g's 32} Wfc[i]*W2[i,j]
__global__ __launch_bounds__(256) void k_pre(
    const float* __restrict__ hidden, const float* __restrict__ W1,
    const float* __restrict__ W2, const float* __restrict__ Wfc,
    float* __restrict__ ws) {
  const int tid = threadIdx.x;

  if (blockIdx.x >= B_ / 4) {
    const int g = blockIdx.x - B_ / 4;
    float acc0 = 0.f, acc1 = 0.f;
#pragma unroll 8
    for (int ii = 0; ii < 32; ++ii) {
      const int i = g * 32 + ii;
      const float f = Wfc[i];
      acc0 += f * W2[(size_t)i * (I_ + F_) + tid];
      acc1 += f * W2[(size_t)i * (I_ + F_) + tid + 256];
    }
    ws[OFF_RP + g * 512 + tid] = acc0;        // r_h partial
    ws[OFF_RP + g * 512 + 256 + tid] = acc1;  // r_v partial
    return;
  }

  __shared__ float h[4][I_];
  __shared__ float red[256];
  const int b0 = blockIdx.x * 4;
#pragma unroll
  for (int k = 0; k < 4; ++k) h[k][tid] = hidden[(size_t)(b0 + k) * I_ + tid];
  __syncthreads();

  const int f = tid;
  const float4* wrow = (const float4*)(W1 + (size_t)f * I_);
  float acc[4] = {0.f, 0.f, 0.f, 0.f};
#pragma unroll 4
  for (int iq = 0; iq < I_ / 4; ++iq) {
    const float4 v = wrow[iq];
    const int i = 4 * iq;
#pragma unroll
    for (int k = 0; k < 4; ++k)
      acc[k] += v.x * h[k][i] + v.y * h[k][i + 1] + v.z * h[k][i + 2] + v.w * h[k][i + 3];
  }
#pragma unroll
  for (int k = 0; k < 4; ++k) ws[OFF_W + (size_t)(b0 + k) * F_ + f] = acc[k];

#pragma unroll
  for (int k = 0; k < 4; ++k) {
    red[tid] = acc[k];
    __syncthreads();
    for (int s = 128; s > 0; s >>= 1) { if (tid < s) red[tid] += red[tid + s]; __syncthreads(); }
    if (tid == 0) ws[OFF_SW + b0 + k] = red[0];
    __syncthreads();
  }
}

// ---------------------------------------------------------------------------
// K1: single pass over inp (1 GB) — R1's proven shape.
//   u[b,t] = inp[b,t,:].w[b,:]   p[b,t] = inp[b,t,:].r_v[:]
// grid (S/32, B), block 256 = 4 waves; wave = one contiguous 1KB row per load,
// dual 6-step shfl_xor reduce. r_v folded from partials once per block.
__global__ __launch_bounds__(256) void k1_scan(
    const float* __restrict__ inp, const float* __restrict__ wsw,
    const float* __restrict__ wsrp,
    float* __restrict__ wsu, float* __restrict__ wsp) {
  const int ROWS = 32;
  const int b = blockIdx.y;
  const int t0 = blockIdx.x * ROWS;
  const int tid = threadIdx.x;
  const int lane = tid & 63;
  const int wid = tid >> 6;

  __shared__ float rv_lds[F_];
  float rv = 0.f;
#pragma unroll
  for (int g = 0; g < NG; ++g) rv += wsrp[g * 512 + 256 + tid];
  rv_lds[tid] = rv;
  __syncthreads();

  const float4 w4  = ((const float4*)(wsw + (size_t)b * F_))[lane];
  const float4 rv4 = ((const float4*)rv_lds)[lane];
  const float* base = inp + ((size_t)b * S_ + t0) * I_;
  float* uo = wsu + (size_t)b * S_ + t0;
  float* po = wsp + (size_t)b * S_ + t0;

#pragma unroll
  for (int rr = 0; rr < ROWS / 4; ++rr) {
    const int row = wid + 4 * rr;
    const float4 in4 = ((const float4*)(base + (size_t)row * I_))[lane];
    float du = in4.x * w4.x + in4.y * w4.y + in4.z * w4.z + in4.w * w4.w;
    float dp = in4.x * rv4.x + in4.y * rv4.y + in4.z * rv4.z + in4.w * rv4.w;
#pragma unroll
    for (int m = 32; m >= 1; m >>= 1) {
      du += __shfl_xor(du, m, 64);
      dp += __shfl_xor(dp, m, 64);
    }
    if (lane == 0) { uo[row] = du; po[row] = dp; }
  }
}

// ---------------------------------------------------------------------------
// K2: per-batch epilogue — R1's proven shape (4 batches/block, LDS-staged u,p,
// per-thread Wc row), with r-partial fold and shfl final reduce.
__global__ __launch_bounds__(256) void k2_epilogue(
    const float* __restrict__ Wc, const float* __restrict__ bc,
    const float* __restrict__ b2, const float* __restrict__ Wfc,
    const float* __restrict__ bfc, const float* __restrict__ hidden,
    const float* __restrict__ wsu, const float* __restrict__ wsp,
    const float* __restrict__ wsSw, const float* __restrict__ wsrp,
    float* __restrict__ out) {
  const int b0 = blockIdx.x * 4;
  const int tid = threadIdx.x;
  const int lane = tid & 63;
  const int wid = tid >> 6;
  __shared__ float u[4][S_];
  __shared__ float p[4][S_];
  __shared__ float redA[4], redB[4];
  __shared__ float wred[4][4];

  // fold r partials
  float rh = 0.f, rv = 0.f;
#pragma unroll
  for (int g = 0; g < NG; ++g) {
    rh += wsrp[g * 512 + tid];
    rv += wsrp[g * 512 + 256 + tid];
  }
  // R = sum(r_v); c0 = Wfc.b2 + bfc
  float t0 = rv, t1 = Wfc[tid] * b2[tid];
#pragma unroll
  for (int m = 32; m >= 1; m >>= 1) {
    t0 += __shfl_xor(t0, m, 64);
    t1 += __shfl_xor(t1, m, 64);
  }
  if (lane == 0) { redA[wid] = t0; redB[wid] = t1; }

#pragma unroll
  for (int k = 0; k < 4; ++k) {
    u[k][tid]       = wsu[(size_t)(b0 + k) * S_ + tid];
    u[k][tid + 256] = wsu[(size_t)(b0 + k) * S_ + tid + 256];
    p[k][tid]       = wsp[(size_t)(b0 + k) * S_ + tid];
    p[k][tid + 256] = wsp[(size_t)(b0 + k) * S_ + tid + 256];
  }
  __syncthreads();

  const float R  = redA[0] + redA[1] + redA[2] + redA[3];
  const float c0 = redB[0] + redB[1] + redB[2] + redB[3] + bfc[0];

  const int x = tid;
  const float4* wrow = (const float4*)(Wc + (size_t)x * S_);
  float ss[4] = {0.f, 0.f, 0.f, 0.f};
  float qs[4] = {0.f, 0.f, 0.f, 0.f};
#pragma unroll 4
  for (int tq = 0; tq < S_ / 4; ++tq) {
    const float4 v = wrow[tq];
    const int t = 4 * tq;
#pragma unroll
    for (int k = 0; k < 4; ++k) {
      ss[k] += v.x * u[k][t] + v.y * u[k][t + 1] + v.z * u[k][t + 2] + v.w * u[k][t + 3];
      qs[k] += v.x * p[k][t] + v.y * p[k][t + 1] + v.z * p[k][t + 2] + v.w * p[k][t + 3];
    }
  }

  const float bcx = bc[x];
#pragma unroll
  for (int k = 0; k < 4; ++k) {
    const float Sw = wsSw[b0 + k];
    const float s = ss[k] + bcx * Sw;
    const float a = 1.f / (1.f + expf(-s));
    float partial = a * (qs[k] + bcx * R) + rh * hidden[(size_t)(b0 + k) * I_ + x];
#pragma unroll
    for (int m = 32; m >= 1; m >>= 1) partial += __shfl_xor(partial, m, 64);
    if (lane == 0) wred[k][wid] = partial;
  }
  __syncthreads();
  if (tid < 4)
    out[b0 + tid] = wred[tid][0] + wred[tid][1] + wred[tid][2] + wred[tid][3] + c0;
}

// ---------------------------------------------------------------------------
extern "C" void kernel_launch(void* const* d_in, const int* in_sizes, int n_in,
                              void* d_out, int out_size, void* d_ws, size_t ws_size,
                              hipStream_t stream) {
  (void)in_sizes; (void)n_in; (void)out_size; (void)ws_size;
  const float* hidden = (const float*)d_in[0];
  const float* inp    = (const float*)d_in[1];
  const float* W1     = (const float*)d_in[2];
  const float* Wc     = (const float*)d_in[3];
  const float* bc     = (const float*)d_in[4];
  const float* W2     = (const float*)d_in[5];
  const float* b2     = (const float*)d_in[6];
  const float* Wfc    = (const float*)d_in[7];
  const float* bfc    = (const float*)d_in[8];
  float* out = (float*)d_out;
  float* ws  = (float*)d_ws;

  hipLaunchKernelGGL(k_pre, dim3(B_ / 4 + NG), dim3(256), 0, stream,
                     hidden, W1, W2, Wfc, ws);
  hipLaunchKernelGGL(k1_scan, dim3(S_ / 32, B_), dim3(256), 0, stream,
                     inp, ws + OFF_W, ws + OFF_RP, ws + OFF_U, ws + OFF_P);
  hipLaunchKernelGGL(k2_epilogue, dim3(B_ / 4), dim3(256), 0, stream,
                     Wc, bc, b2, Wfc, bfc, hidden,
                     ws + OFF_U, ws + OFF_P, ws + OFF_SW, ws + OFF_RP, out);
}